// Round 13
// baseline (493.761 us; speedup 1.0000x reference)
//
#include <hip/hip_runtime.h>
#include <hip/hip_fp16.h>

#define NN 40000
#define NE 640000
#define HID 128
#define NL 5
#define NBLK 157  // ceil(40000/256)
#define LSTRIDE 136  // 128 cols + 8 pad -> 272B rows (16B aligned), 2-way-free banks

typedef __attribute__((ext_vector_type(8))) short bf16x8;
typedef __attribute__((ext_vector_type(4))) float f32x4;

static __device__ __forceinline__ unsigned short f32_to_bf16_rne(float f) {
  unsigned int u = __float_as_uint(f);
  unsigned int lsb = (u >> 16) & 1u;
  u += 0x7fffu + lsb;
  return (unsigned short)(u >> 16);
}
static __device__ __forceinline__ float bf16_to_f32(unsigned short s) {
  return __uint_as_float(((unsigned int)s) << 16);
}

// ---- fused: encoder (blocks 0..19999) + conv_W bf16 hi/lo split (blocks 20000+) ----
__global__ void encoder_wconv_kernel(const float* __restrict__ x, const float* __restrict__ encW,
                                     const float* __restrict__ encb, __half* __restrict__ h,
                                     const float* __restrict__ convW,
                                     unsigned short* __restrict__ whi,
                                     unsigned short* __restrict__ wlo) {
  int b = blockIdx.x;
  if (b < 20000) {
    int gid = b * 256 + threadIdx.x;  // < NN*HID
    int n = gid >> 7, k = gid & 127;
    const float* xp = x + n * 7;
    const float* wp = encW + k * 7;
    float acc = encb[k];
#pragma unroll
    for (int i = 0; i < 7; ++i) acc += xp[i] * wp[i];
    h[gid] = __float2half(acc);
  } else {
    int i = (b - 20000) * 256 + threadIdx.x;
    if (i < NL * HID * HID) {
      float w = convW[i];
      unsigned short hi = f32_to_bf16_rne(w);
      unsigned short lo = f32_to_bf16_rne(w - bf16_to_f32(hi));
      whi[i] = hi;
      wlo[i] = lo;
    }
  }
}

// ---------------- CSR build ----------------
__global__ void hist_kernel(const int* __restrict__ dst, int* __restrict__ cnt,
                            int* __restrict__ rank) {
  int e = blockIdx.x * blockDim.x + threadIdx.x;
  if (e < NE) rank[e] = atomicAdd(&cnt[dst[e]], 1);
}

__global__ void partial_kernel(const int* __restrict__ cnt, int* __restrict__ blocksum) {
  __shared__ int red[4];
  int t = threadIdx.x;
  int idx = blockIdx.x * 256 + t;
  int v = idx < NN ? cnt[idx] : 0;
#pragma unroll
  for (int off = 32; off > 0; off >>= 1) v += __shfl_xor(v, off, 64);
  if ((t & 63) == 0) red[t >> 6] = v;
  __syncthreads();
  if (t == 0) blocksum[blockIdx.x] = red[0] + red[1] + red[2] + red[3];
}

__global__ void scan_small_kernel(const int* __restrict__ blocksum, int* __restrict__ blockoff,
                                  int* __restrict__ row_ptr) {
  __shared__ int sh[256];
  int t = threadIdx.x;
  int v = t < NBLK ? blocksum[t] : 0;
  sh[t] = v;
  __syncthreads();
  for (int off = 1; off < 256; off <<= 1) {
    int u = (t >= off) ? sh[t - off] : 0;
    __syncthreads();
    sh[t] += u;
    __syncthreads();
  }
  if (t < NBLK) blockoff[t] = sh[t] - v;
  if (t == 255) row_ptr[NN] = sh[255];
}

__global__ void rowptr_kernel(const int* __restrict__ cnt, const int* __restrict__ blockoff,
                              int* __restrict__ row_ptr) {
  __shared__ int sh[256];
  int t = threadIdx.x;
  int idx = blockIdx.x * 256 + t;
  int v = idx < NN ? cnt[idx] : 0;
  sh[t] = v;
  __syncthreads();
  for (int off = 1; off < 256; off <<= 1) {
    int u = (t >= off) ? sh[t - off] : 0;
    __syncthreads();
    sh[t] += u;
    __syncthreads();
  }
  if (idx < NN) row_ptr[idx] = blockoff[blockIdx.x] + sh[t] - v;
}

// pure read + ONE 8B store per edge (no atomic: rank precomputed in hist).
__global__ void scatter_kernel(const int* __restrict__ src, const int* __restrict__ dst,
                               const float* __restrict__ dist,
                               const int* __restrict__ row_ptr, const int* __restrict__ rank,
                               int2* __restrict__ csr_ew) {
  int e = blockIdx.x * blockDim.x + threadIdx.x;
  if (e >= NE) return;
  int pos = row_ptr[dst[e]] + rank[e];
  float dd = dist[e] + 1e-6f;
  float w = 1.0f / (dd * dd);
  csr_ew[pos] = make_int2(src[e], (int)__float_as_uint(w));
}

__global__ void wsum_kernel(const int* __restrict__ row_ptr, const int2* __restrict__ csr_ew,
                            float* __restrict__ wsum) {
  int n = blockIdx.x * blockDim.x + threadIdx.x;
  if (n >= NN) return;
  int s = row_ptr[n], e = row_ptr[n + 1];
  float acc = 0.f;
  for (int i = s; i < e; ++i) acc += __uint_as_float((unsigned)csr_ew[i].y);
  wsum[n] = acc;
}

// ---------------- fused per-layer: gather-aggregate -> LDS -> MFMA linear ----------------
// Block = 4 waves x 16 nodes. Phase 1: each wave aggregates its 16 nodes (R12's
// forced-MLP gather) into its OWN LDS region as bf16 hi/lo. Phase 2: same wave
// consumes only its own rows -> no barrier; waves/blocks pipeline gather vs MFMA.
// h is double-buffered (hin -> hout) since blocks read random hin rows while
// others write their output tiles.
__global__ void __launch_bounds__(256) fused_layer_kernel(
    const __half* __restrict__ hin, const int* __restrict__ row_ptr,
    const int2* __restrict__ csr_ew,
    const unsigned short* __restrict__ whi, const unsigned short* __restrict__ wlo,
    const float* __restrict__ wsum, const float* __restrict__ b,
    __half* __restrict__ hout) {
  __shared__ __align__(16) unsigned short sAh[4][16][LSTRIDE];
  __shared__ __align__(16) unsigned short sAl[4][16][LSTRIDE];
  int wave = threadIdx.x >> 6;
  int lane = threadIdx.x & 63;
  int node0 = blockIdx.x * 64 + wave * 16;  // this wave's 16 nodes

  // ---- phase 1: aggregate 16 nodes into LDS ----
  const __half* hp = hin + lane * 2;  // this lane's 2 columns
  for (int t = 0; t < 16; ++t) {
    int node = node0 + t;
    int s = __builtin_amdgcn_readfirstlane(row_ptr[node]);
    int e = __builtin_amdgcn_readfirstlane(row_ptr[node + 1]);
    float ax = 0.f, ay = 0.f;
    int i = s;
    for (; i + 16 <= e; i += 16) {
      unsigned hv[16];
      float wv[16];
#pragma unroll
      for (int u = 0; u < 16; ++u) {
        int2 p = csr_ew[i + u];  // wave-uniform -> s_load
        wv[u] = __uint_as_float((unsigned)p.y);
        hv[u] = *reinterpret_cast<const unsigned*>(hp + p.x * HID);
      }
#pragma unroll
      for (int u = 0; u < 16; ++u) {
        float2 f = __half22float2(*reinterpret_cast<__half2*>(&hv[u]));
        ax += wv[u] * f.x;
        ay += wv[u] * f.y;
      }
    }
    for (; i < e; ++i) {
      int2 p = csr_ew[i];
      float w = __uint_as_float((unsigned)p.y);
      float2 f = __half22float2(*reinterpret_cast<const __half2*>(hp + p.x * HID));
      ax += w * f.x;
      ay += w * f.y;
    }
    unsigned short hx = f32_to_bf16_rne(ax), lx = f32_to_bf16_rne(ax - bf16_to_f32(hx));
    unsigned short hy = f32_to_bf16_rne(ay), ly = f32_to_bf16_rne(ay - bf16_to_f32(hy));
    ushort2 hv2 = {hx, hy}, lv2 = {lx, ly};
    *reinterpret_cast<ushort2*>(&sAh[wave][t][lane * 2]) = hv2;
    *reinterpret_cast<ushort2*>(&sAl[wave][t][lane * 2]) = lv2;
  }

  // ---- phase 2: h = relu(agg @ W^T + b*wsum) via split-bf16 MFMA ----
  // wave = 16 nodes x 128 outs, K=128; a*w ~= ah*wh + ah*wl + al*wh (fp32 acc).
  // D: col(kout)=lane&15, row(node)=(lane>>4)*4+reg [guide §3, m89-verified].
  int mrow = lane & 15;
  int kc = (lane >> 4) * 8;

  f32x4 acc[8];
#pragma unroll
  for (int t = 0; t < 8; ++t) acc[t] = (f32x4){0.f, 0.f, 0.f, 0.f};

#pragma unroll
  for (int s = 0; s < 4; ++s) {
    int joff = s * 32 + kc;
    bf16x8 ah = *reinterpret_cast<const bf16x8*>(&sAh[wave][mrow][joff]);
    bf16x8 al = *reinterpret_cast<const bf16x8*>(&sAl[wave][mrow][joff]);
#pragma unroll
    for (int t = 0; t < 8; ++t) {
      bf16x8 bh = *reinterpret_cast<const bf16x8*>(whi + (t * 16 + mrow) * HID + joff);
      bf16x8 bl = *reinterpret_cast<const bf16x8*>(wlo + (t * 16 + mrow) * HID + joff);
      acc[t] = __builtin_amdgcn_mfma_f32_16x16x32_bf16(ah, bh, acc[t], 0, 0, 0);
      acc[t] = __builtin_amdgcn_mfma_f32_16x16x32_bf16(ah, bl, acc[t], 0, 0, 0);
      acc[t] = __builtin_amdgcn_mfma_f32_16x16x32_bf16(al, bh, acc[t], 0, 0, 0);
    }
  }

  int nodeBase = node0 + (lane >> 4) * 4;
  float ws4[4];
#pragma unroll
  for (int r = 0; r < 4; ++r) ws4[r] = wsum[nodeBase + r];
#pragma unroll
  for (int t = 0; t < 8; ++t) {
    int kout = t * 16 + mrow;
    float bk = b[kout];
#pragma unroll
    for (int r = 0; r < 4; ++r) {
      float v = acc[t][r] + bk * ws4[r];
      hout[(nodeBase + r) * HID + kout] = __float2half(fmaxf(v, 0.f));
    }
  }
}

// ---------------- cluster softmax head (wave per node) ----------------
__global__ void cluster_kernel(const __half* __restrict__ h, const float* __restrict__ cW,
                               const float* __restrict__ cb, float* __restrict__ out) {
  int wid = (blockIdx.x * blockDim.x + threadIdx.x) >> 6;
  int lane = threadIdx.x & 63;
  if (wid >= NN) return;
  float h0 = __half2float(h[wid * HID + lane]);
  float h1 = __half2float(h[wid * HID + 64 + lane]);
  float logit[3];
#pragma unroll
  for (int c = 0; c < 3; ++c) {
    float p = h0 * cW[c * HID + lane] + h1 * cW[c * HID + 64 + lane];
#pragma unroll
    for (int off = 32; off > 0; off >>= 1) p += __shfl_xor(p, off, 64);
    logit[c] = p + cb[c];
  }
  if (lane == 0) {
    float m = fmaxf(logit[0], fmaxf(logit[1], logit[2]));
    float e0 = expf(logit[0] - m), e1 = expf(logit[1] - m), e2 = expf(logit[2] - m);
    float inv = 1.0f / (e0 + e1 + e2);
    out[wid * 3 + 0] = e0 * inv;
    out[wid * 3 + 1] = e1 * inv;
    out[wid * 3 + 2] = e2 * inv;
  }
}

// ---------------- energy head: two-stage column reduction ----------------
__global__ void colsum_part_kernel(const __half* __restrict__ h, float* __restrict__ partial) {
  int t = threadIdx.x;
  int col = t & 127;
  int lane_id = blockIdx.x * 2 + (t >> 7);  // [0, 2048)
  float acc = 0.f;
  for (int r = lane_id; r < NN; r += 2048) acc += __half2float(h[r * HID + col]);
  partial[lane_id * HID + col] = acc;
}

__global__ void energy_final_kernel(const float* __restrict__ partial,
                                    const float* __restrict__ eW, const float* __restrict__ eb,
                                    float* __restrict__ out) {
  __shared__ float sh[8][HID];
  __shared__ float red[2];
  int t = threadIdx.x;
  int col = t & 127;
  int slot = t >> 7;  // 0..7
  float acc = 0.f;
  for (int i = 0; i < 256; ++i) acc += partial[(slot + 8 * i) * HID + col];
  sh[slot][col] = acc;
  __syncthreads();
  if (t < 128) {
    float s = 0.f;
#pragma unroll
    for (int j = 0; j < 8; ++j) s += sh[j][t];
    float v = s * (1.0f / NN) * eW[t];
#pragma unroll
    for (int off = 32; off > 0; off >>= 1) v += __shfl_xor(v, off, 64);
    if ((t & 63) == 0) red[t >> 6] = v;
  }
  __syncthreads();
  if (t == 0) {
    float e = red[0] + red[1] + eb[0];
    out[NN * 3] = e;
    out[NN * 3 + 1] = (e < -1.0f) ? 1.0f : 0.0f;
  }
}

extern "C" void kernel_launch(void* const* d_in, const int* in_sizes, int n_in,
                              void* d_out, int out_size, void* d_ws, size_t ws_size,
                              hipStream_t stream) {
  const float* x    = (const float*)d_in[0];
  const int*   ei   = (const int*)d_in[1];
  const float* dist = (const float*)d_in[2];
  const float* encW = (const float*)d_in[3];
  const float* encb = (const float*)d_in[4];
  const float* convW = (const float*)d_in[5];
  const float* convb = (const float*)d_in[6];
  const float* cW   = (const float*)d_in[7];
  const float* cb   = (const float*)d_in[8];
  const float* eW   = (const float*)d_in[9];
  const float* eb   = (const float*)d_in[10];
  float* out = (float*)d_out;

  // workspace layout (bytes)
  char* ws = (char*)d_ws;
  __half*         h1      = (__half*)        (ws + 0);           // 10,240,000
  __half*         h2      = (__half*)        (ws + 10240000);    // 10,240,000 (dbuf)
  char*           scratch = (char*)          (ws + 20480000);    // 10,240,000 (scan+colsum)
  int2*           csr_ew  = (int2*)          (ws + 30720000);    //  5,120,000
  int*            row_ptr = (int*)           (ws + 35840000);    //    160,064
  int*            cnt     = (int*)           (ws + 36000064);    //    160,000
  float*          wsum    = (float*)         (ws + 36160064);    //    160,000
  unsigned short* whi5    = (unsigned short*)(ws + 36320064);    //    163,840
  unsigned short* wlo5    = (unsigned short*)(ws + 36483904);    //    163,840
  int*            rank    = (int*)           (ws + 36647744);    //  2,560,000
  if (ws_size < (size_t)39207744) return;  // insufficient scratch — fail visibly

  int*   blocksum = (int*)scratch;
  int*   blockoff = (int*)scratch + 512;
  float* partial  = (float*)scratch;  // 2048*128 floats = 1 MB (used after CSR build)

  const int* srcI = ei;
  const int* dstI = ei + NE;

  hipMemsetAsync(cnt, 0, 160000, stream);

  encoder_wconv_kernel<<<20320, 256, 0, stream>>>(x, encW, encb, h1, convW, whi5, wlo5);

  hist_kernel<<<(NE + 255) / 256, 256, 0, stream>>>(dstI, cnt, rank);
  partial_kernel<<<NBLK, 256, 0, stream>>>(cnt, blocksum);
  scan_small_kernel<<<1, 256, 0, stream>>>(blocksum, blockoff, row_ptr);
  rowptr_kernel<<<NBLK, 256, 0, stream>>>(cnt, blockoff, row_ptr);
  scatter_kernel<<<(NE + 255) / 256, 256, 0, stream>>>(srcI, dstI, dist, row_ptr, rank, csr_ew);
  wsum_kernel<<<(NN + 255) / 256, 256, 0, stream>>>(row_ptr, csr_ew, wsum);

  __half* hin = h1;
  __half* hout = h2;
  for (int l = 0; l < NL; ++l) {
    fused_layer_kernel<<<NN / 64, 256, 0, stream>>>(hin, row_ptr, csr_ew,
                                                    whi5 + (size_t)l * HID * HID,
                                                    wlo5 + (size_t)l * HID * HID,
                                                    wsum, convb + (size_t)l * HID, hout);
    __half* tmp = hin; hin = hout; hout = tmp;
  }
  // after 5 layers, final h is in hin (= h2)

  cluster_kernel<<<(NN * 64 + 255) / 256, 256, 0, stream>>>(hin, cW, cb, out);
  colsum_part_kernel<<<1024, 256, 0, stream>>>(hin, partial);
  energy_final_kernel<<<1, 1024, 0, stream>>>(partial, eW, eb, out);
}

// Round 14
// 381.590 us; speedup vs baseline: 1.2940x; 1.2940x over previous
//
#include <hip/hip_runtime.h>
#include <hip/hip_fp16.h>

#define NN 40000
#define NE 640000
#define HID 128
#define NL 5
#define NBLK 157  // ceil(40000/256)

typedef __attribute__((ext_vector_type(8))) short bf16x8;
typedef __attribute__((ext_vector_type(4))) float f32x4;

static __device__ __forceinline__ unsigned short f32_to_bf16_rne(float f) {
  unsigned int u = __float_as_uint(f);
  unsigned int lsb = (u >> 16) & 1u;
  u += 0x7fffu + lsb;
  return (unsigned short)(u >> 16);
}
static __device__ __forceinline__ float bf16_to_f32(unsigned short s) {
  return __uint_as_float(((unsigned int)s) << 16);
}

// ---- fused: encoder (blocks 0..19999) + conv_W bf16 hi/lo split (blocks 20000+) ----
__global__ void encoder_wconv_kernel(const float* __restrict__ x, const float* __restrict__ encW,
                                     const float* __restrict__ encb, __half* __restrict__ h,
                                     const float* __restrict__ convW,
                                     unsigned short* __restrict__ whi,
                                     unsigned short* __restrict__ wlo) {
  int b = blockIdx.x;
  if (b < 20000) {
    int gid = b * 256 + threadIdx.x;  // < NN*HID
    int n = gid >> 7, k = gid & 127;
    const float* xp = x + n * 7;
    const float* wp = encW + k * 7;
    float acc = encb[k];
#pragma unroll
    for (int i = 0; i < 7; ++i) acc += xp[i] * wp[i];
    h[gid] = __float2half(acc);
  } else {
    int i = (b - 20000) * 256 + threadIdx.x;
    if (i < NL * HID * HID) {
      float w = convW[i];
      unsigned short hi = f32_to_bf16_rne(w);
      unsigned short lo = f32_to_bf16_rne(w - bf16_to_f32(hi));
      whi[i] = hi;
      wlo[i] = lo;
    }
  }
}

// ---------------- CSR build ----------------
__global__ void hist_kernel(const int* __restrict__ dst, int* __restrict__ cnt,
                            int* __restrict__ rank) {
  int e = blockIdx.x * blockDim.x + threadIdx.x;
  if (e < NE) rank[e] = atomicAdd(&cnt[dst[e]], 1);
}

__global__ void partial_kernel(const int* __restrict__ cnt, int* __restrict__ blocksum) {
  __shared__ int red[4];
  int t = threadIdx.x;
  int idx = blockIdx.x * 256 + t;
  int v = idx < NN ? cnt[idx] : 0;
#pragma unroll
  for (int off = 32; off > 0; off >>= 1) v += __shfl_xor(v, off, 64);
  if ((t & 63) == 0) red[t >> 6] = v;
  __syncthreads();
  if (t == 0) blocksum[blockIdx.x] = red[0] + red[1] + red[2] + red[3];
}

__global__ void scan_small_kernel(const int* __restrict__ blocksum, int* __restrict__ blockoff,
                                  int* __restrict__ row_ptr) {
  __shared__ int sh[256];
  int t = threadIdx.x;
  int v = t < NBLK ? blocksum[t] : 0;
  sh[t] = v;
  __syncthreads();
  for (int off = 1; off < 256; off <<= 1) {
    int u = (t >= off) ? sh[t - off] : 0;
    __syncthreads();
    sh[t] += u;
    __syncthreads();
  }
  if (t < NBLK) blockoff[t] = sh[t] - v;
  if (t == 255) row_ptr[NN] = sh[255];
}

__global__ void rowptr_kernel(const int* __restrict__ cnt, const int* __restrict__ blockoff,
                              int* __restrict__ row_ptr) {
  __shared__ int sh[256];
  int t = threadIdx.x;
  int idx = blockIdx.x * 256 + t;
  int v = idx < NN ? cnt[idx] : 0;
  sh[t] = v;
  __syncthreads();
  for (int off = 1; off < 256; off <<= 1) {
    int u = (t >= off) ? sh[t - off] : 0;
    __syncthreads();
    sh[t] += u;
    __syncthreads();
  }
  if (idx < NN) row_ptr[idx] = blockoff[blockIdx.x] + sh[t] - v;
}

// pure read + ONE 8B store per edge (no atomic: rank precomputed in hist).
__global__ void scatter_kernel(const int* __restrict__ src, const int* __restrict__ dst,
                               const float* __restrict__ dist,
                               const int* __restrict__ row_ptr, const int* __restrict__ rank,
                               int2* __restrict__ csr_ew) {
  int e = blockIdx.x * blockDim.x + threadIdx.x;
  if (e >= NE) return;
  int pos = row_ptr[dst[e]] + rank[e];
  float dd = dist[e] + 1e-6f;
  float w = 1.0f / (dd * dd);
  csr_ew[pos] = make_int2(src[e], (int)__float_as_uint(w));
}

__global__ void wsum_kernel(const int* __restrict__ row_ptr, const int2* __restrict__ csr_ew,
                            float* __restrict__ wsum) {
  int n = blockIdx.x * blockDim.x + threadIdx.x;
  if (n >= NN) return;
  int s = row_ptr[n], e = row_ptr[n + 1];
  float acc = 0.f;
  for (int i = s; i < e; ++i) acc += __uint_as_float((unsigned)csr_ew[i].y);
  wsum[n] = acc;
}

// ---------------- per-layer: aggregate (wave per node, 4 edges per VMEM instr) -------
// 16 lanes per edge x 16B/lane (uint4) = one full 256B fp16 row; a wave covers 4
// edges per global_load_dwordx4. Main loop: clamp-free 16-edge strips (4 quads in
// flight); tail: <=3 clamped quads with w=0 (exact). Group g accumulates edges
// g, g+4, ...; epilogue reduces over g with 2 shfl_xor (fp32 reorder only).
__global__ void aggregate_kernel(const __half* __restrict__ h, const int* __restrict__ row_ptr,
                                 const int2* __restrict__ csr_ew,
                                 unsigned short* __restrict__ aggh,
                                 unsigned short* __restrict__ aggl) {
  int wid = (blockIdx.x * blockDim.x + threadIdx.x) >> 6;
  int lane = threadIdx.x & 63;
  if (wid >= NN) return;
  int s = __builtin_amdgcn_readfirstlane(row_ptr[wid]);
  int e = __builtin_amdgcn_readfirstlane(row_ptr[wid + 1]);
  int g = lane >> 4;   // edge slot within a quad
  int k = lane & 15;   // col octet: cols [8k, 8k+8)
  const __half* hp = h + k * 8;
  float a[8] = {0.f, 0.f, 0.f, 0.f, 0.f, 0.f, 0.f, 0.f};
  int i = s;
  for (; i + 16 <= e; i += 16) {  // clamp-free main strips
    uint4 hv[4];
    float wv[4];
#pragma unroll
    for (int u = 0; u < 4; ++u) {
      int2 p = csr_ew[i + u * 4 + g];
      wv[u] = __uint_as_float((unsigned)p.y);
      hv[u] = *reinterpret_cast<const uint4*>(hp + (size_t)p.x * HID);
    }
#pragma unroll
    for (int u = 0; u < 4; ++u) {
      const __half2* q = reinterpret_cast<const __half2*>(&hv[u]);
#pragma unroll
      for (int c = 0; c < 4; ++c) {
        float2 f = __half22float2(q[c]);
        a[2 * c] += wv[u] * f.x;
        a[2 * c + 1] += wv[u] * f.y;
      }
    }
  }
  for (; i < e; i += 4) {  // tail quads (clamped, w=0 pads vanish exactly)
    int j = i + g;
    int jc = j < e ? j : e - 1;
    int2 p = csr_ew[jc];
    float w = (j < e) ? __uint_as_float((unsigned)p.y) : 0.f;
    uint4 hv = *reinterpret_cast<const uint4*>(hp + (size_t)p.x * HID);
    const __half2* q = reinterpret_cast<const __half2*>(&hv);
#pragma unroll
    for (int c = 0; c < 4; ++c) {
      float2 f = __half22float2(q[c]);
      a[2 * c] += w * f.x;
      a[2 * c + 1] += w * f.y;
    }
  }
  // reduce the 4 group partials per column
#pragma unroll
  for (int c = 0; c < 8; ++c) {
    a[c] += __shfl_xor(a[c], 16, 64);
    a[c] += __shfl_xor(a[c], 32, 64);
  }
  if (g == 0) {
    unsigned short hh[8], ll[8];
#pragma unroll
    for (int c = 0; c < 8; ++c) {
      hh[c] = f32_to_bf16_rne(a[c]);
      ll[c] = f32_to_bf16_rne(a[c] - bf16_to_f32(hh[c]));
    }
    *reinterpret_cast<uint4*>(aggh + wid * HID + k * 8) = *reinterpret_cast<const uint4*>(hh);
    *reinterpret_cast<uint4*>(aggl + wid * HID + k * 8) = *reinterpret_cast<const uint4*>(ll);
  }
}

// ---------------- per-layer: h = relu(agg @ W^T + b * wsum) via split-bf16 MFMA ----------
// wave = 16 nodes x 128 outputs, K=128. a*w ~= ah*wh + ah*wl + al*wh (fp32 acc).
// D: col(kout)=lane&15, row(node)=(lane>>4)*4+reg  [guide §3, m89-verified].
__global__ void __launch_bounds__(256) mfma_linear_kernel(
    const unsigned short* __restrict__ aggh, const unsigned short* __restrict__ aggl,
    const unsigned short* __restrict__ whi, const unsigned short* __restrict__ wlo,
    const float* __restrict__ wsum, const float* __restrict__ b, __half* __restrict__ h) {
  int wave = threadIdx.x >> 6;
  int lane = threadIdx.x & 63;
  int node0 = blockIdx.x * 64 + wave * 16;
  int mrow = lane & 15;
  int kc = (lane >> 4) * 8;

  const unsigned short* pah = aggh + (node0 + mrow) * HID;
  const unsigned short* pal = aggl + (node0 + mrow) * HID;

  f32x4 acc[8];
#pragma unroll
  for (int t = 0; t < 8; ++t) acc[t] = (f32x4){0.f, 0.f, 0.f, 0.f};

#pragma unroll
  for (int s = 0; s < 4; ++s) {
    int joff = s * 32 + kc;
    bf16x8 ah = *reinterpret_cast<const bf16x8*>(pah + joff);
    bf16x8 al = *reinterpret_cast<const bf16x8*>(pal + joff);
#pragma unroll
    for (int t = 0; t < 8; ++t) {
      bf16x8 bh = *reinterpret_cast<const bf16x8*>(whi + (t * 16 + mrow) * HID + joff);
      bf16x8 bl = *reinterpret_cast<const bf16x8*>(wlo + (t * 16 + mrow) * HID + joff);
      acc[t] = __builtin_amdgcn_mfma_f32_16x16x32_bf16(ah, bh, acc[t], 0, 0, 0);
      acc[t] = __builtin_amdgcn_mfma_f32_16x16x32_bf16(ah, bl, acc[t], 0, 0, 0);
      acc[t] = __builtin_amdgcn_mfma_f32_16x16x32_bf16(al, bh, acc[t], 0, 0, 0);
    }
  }

  int nodeBase = node0 + (lane >> 4) * 4;
  float ws4[4];
#pragma unroll
  for (int r = 0; r < 4; ++r) ws4[r] = wsum[nodeBase + r];
#pragma unroll
  for (int t = 0; t < 8; ++t) {
    int kout = t * 16 + mrow;
    float bk = b[kout];
#pragma unroll
    for (int r = 0; r < 4; ++r) {
      float v = acc[t][r] + bk * ws4[r];
      h[(nodeBase + r) * HID + kout] = __float2half(fmaxf(v, 0.f));
    }
  }
}

// ---------------- cluster softmax head (wave per node) ----------------
__global__ void cluster_kernel(const __half* __restrict__ h, const float* __restrict__ cW,
                               const float* __restrict__ cb, float* __restrict__ out) {
  int wid = (blockIdx.x * blockDim.x + threadIdx.x) >> 6;
  int lane = threadIdx.x & 63;
  if (wid >= NN) return;
  float h0 = __half2float(h[wid * HID + lane]);
  float h1 = __half2float(h[wid * HID + 64 + lane]);
  float logit[3];
#pragma unroll
  for (int c = 0; c < 3; ++c) {
    float p = h0 * cW[c * HID + lane] + h1 * cW[c * HID + 64 + lane];
#pragma unroll
    for (int off = 32; off > 0; off >>= 1) p += __shfl_xor(p, off, 64);
    logit[c] = p + cb[c];
  }
  if (lane == 0) {
    float m = fmaxf(logit[0], fmaxf(logit[1], logit[2]));
    float e0 = expf(logit[0] - m), e1 = expf(logit[1] - m), e2 = expf(logit[2] - m);
    float inv = 1.0f / (e0 + e1 + e2);
    out[wid * 3 + 0] = e0 * inv;
    out[wid * 3 + 1] = e1 * inv;
    out[wid * 3 + 2] = e2 * inv;
  }
}

// ---------------- energy head: two-stage column reduction ----------------
__global__ void colsum_part_kernel(const __half* __restrict__ h, float* __restrict__ partial) {
  int t = threadIdx.x;
  int col = t & 127;
  int lane_id = blockIdx.x * 2 + (t >> 7);  // [0, 2048)
  float acc = 0.f;
  for (int r = lane_id; r < NN; r += 2048) acc += __half2float(h[r * HID + col]);
  partial[lane_id * HID + col] = acc;
}

__global__ void energy_final_kernel(const float* __restrict__ partial,
                                    const float* __restrict__ eW, const float* __restrict__ eb,
                                    float* __restrict__ out) {
  __shared__ float sh[8][HID];
  __shared__ float red[2];
  int t = threadIdx.x;
  int col = t & 127;
  int slot = t >> 7;  // 0..7
  float acc = 0.f;
  for (int i = 0; i < 256; ++i) acc += partial[(slot + 8 * i) * HID + col];
  sh[slot][col] = acc;
  __syncthreads();
  if (t < 128) {
    float s = 0.f;
#pragma unroll
    for (int j = 0; j < 8; ++j) s += sh[j][t];
    float v = s * (1.0f / NN) * eW[t];
#pragma unroll
    for (int off = 32; off > 0; off >>= 1) v += __shfl_xor(v, off, 64);
    if ((t & 63) == 0) red[t >> 6] = v;
  }
  __syncthreads();
  if (t == 0) {
    float e = red[0] + red[1] + eb[0];
    out[NN * 3] = e;
    out[NN * 3 + 1] = (e < -1.0f) ? 1.0f : 0.0f;
  }
}

extern "C" void kernel_launch(void* const* d_in, const int* in_sizes, int n_in,
                              void* d_out, int out_size, void* d_ws, size_t ws_size,
                              hipStream_t stream) {
  const float* x    = (const float*)d_in[0];
  const int*   ei   = (const int*)d_in[1];
  const float* dist = (const float*)d_in[2];
  const float* encW = (const float*)d_in[3];
  const float* encb = (const float*)d_in[4];
  const float* convW = (const float*)d_in[5];
  const float* convb = (const float*)d_in[6];
  const float* cW   = (const float*)d_in[7];
  const float* cb   = (const float*)d_in[8];
  const float* eW   = (const float*)d_in[9];
  const float* eb   = (const float*)d_in[10];
  float* out = (float*)d_out;

  // workspace layout (bytes)
  char* ws = (char*)d_ws;
  __half*         h       = (__half*)        (ws + 0);           // 10,240,000
  unsigned short* aggh    = (unsigned short*)(ws + 10240000);    // 10,240,000
  unsigned short* aggl    = (unsigned short*)(ws + 20480000);    // 10,240,000
  int2*           csr_ew  = (int2*)          (ws + 30720000);    //  5,120,000
  int*            row_ptr = (int*)           (ws + 35840000);    //    160,064
  int*            cnt     = (int*)           (ws + 36000064);    //    160,000
  float*          wsum    = (float*)         (ws + 36160064);    //    160,000
  unsigned short* whi5    = (unsigned short*)(ws + 36320064);    //    163,840
  unsigned short* wlo5    = (unsigned short*)(ws + 36483904);    //    163,840
  int*            rank    = (int*)           (ws + 36647744);    //  2,560,000
  if (ws_size < (size_t)39207744) return;  // insufficient scratch — fail visibly

  // aggh region is dead until the first aggregate -> scan scratch lives there;
  // and dead again after the last mfma_linear -> colsum partials live there.
  int*   blocksum = (int*)aggh;
  int*   blockoff = (int*)aggh + 512;
  float* partial  = (float*)aggh;  // 2048*128 floats = 1 MB

  const int* srcI = ei;
  const int* dstI = ei + NE;

  hipMemsetAsync(cnt, 0, 160000, stream);

  encoder_wconv_kernel<<<20320, 256, 0, stream>>>(x, encW, encb, h, convW, whi5, wlo5);

  hist_kernel<<<(NE + 255) / 256, 256, 0, stream>>>(dstI, cnt, rank);
  partial_kernel<<<NBLK, 256, 0, stream>>>(cnt, blocksum);
  scan_small_kernel<<<1, 256, 0, stream>>>(blocksum, blockoff, row_ptr);
  rowptr_kernel<<<NBLK, 256, 0, stream>>>(cnt, blockoff, row_ptr);
  scatter_kernel<<<(NE + 255) / 256, 256, 0, stream>>>(srcI, dstI, dist, row_ptr, rank, csr_ew);
  wsum_kernel<<<(NN + 255) / 256, 256, 0, stream>>>(row_ptr, csr_ew, wsum);

  for (int l = 0; l < NL; ++l) {
    aggregate_kernel<<<(NN * 64 + 255) / 256, 256, 0, stream>>>(h, row_ptr, csr_ew, aggh, aggl);
    mfma_linear_kernel<<<NN / 64, 256, 0, stream>>>(aggh, aggl,
                                                    whi5 + (size_t)l * HID * HID,
                                                    wlo5 + (size_t)l * HID * HID,
                                                    wsum, convb + (size_t)l * HID, h);
  }

  cluster_kernel<<<(NN * 64 + 255) / 256, 256, 0, stream>>>(h, cW, cb, out);
  colsum_part_kernel<<<1024, 256, 0, stream>>>(h, partial);
  energy_final_kernel<<<1, 1024, 0, stream>>>(partial, eW, eb, out);
}

// Round 15
// 331.137 us; speedup vs baseline: 1.4911x; 1.1524x over previous
//
#include <hip/hip_runtime.h>
#include <hip/hip_fp16.h>

#define NN 40000
#define NE 640000
#define HID 128
#define NL 5
#define NBLK 157  // ceil(40000/256)
#define LSTRIDE 136  // 128 + 8 pad shorts -> 272B rows; 2-way bank aliasing only (free)

typedef __attribute__((ext_vector_type(8))) short bf16x8;
typedef __attribute__((ext_vector_type(4))) float f32x4;

static __device__ __forceinline__ unsigned short f32_to_bf16_rne(float f) {
  unsigned int u = __float_as_uint(f);
  unsigned int lsb = (u >> 16) & 1u;
  u += 0x7fffu + lsb;
  return (unsigned short)(u >> 16);
}
static __device__ __forceinline__ float bf16_to_f32(unsigned short s) {
  return __uint_as_float(((unsigned int)s) << 16);
}

// ---- fused: encoder (blocks 0..19999) + conv_W bf16 hi/lo split (blocks 20000+) ----
__global__ void encoder_wconv_kernel(const float* __restrict__ x, const float* __restrict__ encW,
                                     const float* __restrict__ encb, __half* __restrict__ h,
                                     const float* __restrict__ convW,
                                     unsigned short* __restrict__ whi,
                                     unsigned short* __restrict__ wlo) {
  int b = blockIdx.x;
  if (b < 20000) {
    int gid = b * 256 + threadIdx.x;  // < NN*HID
    int n = gid >> 7, k = gid & 127;
    const float* xp = x + n * 7;
    const float* wp = encW + k * 7;
    float acc = encb[k];
#pragma unroll
    for (int i = 0; i < 7; ++i) acc += xp[i] * wp[i];
    h[gid] = __float2half(acc);
  } else {
    int i = (b - 20000) * 256 + threadIdx.x;
    if (i < NL * HID * HID) {
      float w = convW[i];
      unsigned short hi = f32_to_bf16_rne(w);
      unsigned short lo = f32_to_bf16_rne(w - bf16_to_f32(hi));
      whi[i] = hi;
      wlo[i] = lo;
    }
  }
}

// ---------------- CSR build ----------------
__global__ void hist_kernel(const int* __restrict__ dst, int* __restrict__ cnt,
                            int* __restrict__ rank) {
  int e = blockIdx.x * blockDim.x + threadIdx.x;
  if (e < NE) rank[e] = atomicAdd(&cnt[dst[e]], 1);
}

__global__ void partial_kernel(const int* __restrict__ cnt, int* __restrict__ blocksum) {
  __shared__ int red[4];
  int t = threadIdx.x;
  int idx = blockIdx.x * 256 + t;
  int v = idx < NN ? cnt[idx] : 0;
#pragma unroll
  for (int off = 32; off > 0; off >>= 1) v += __shfl_xor(v, off, 64);
  if ((t & 63) == 0) red[t >> 6] = v;
  __syncthreads();
  if (t == 0) blocksum[blockIdx.x] = red[0] + red[1] + red[2] + red[3];
}

__global__ void scan_small_kernel(const int* __restrict__ blocksum, int* __restrict__ blockoff,
                                  int* __restrict__ row_ptr) {
  __shared__ int sh[256];
  int t = threadIdx.x;
  int v = t < NBLK ? blocksum[t] : 0;
  sh[t] = v;
  __syncthreads();
  for (int off = 1; off < 256; off <<= 1) {
    int u = (t >= off) ? sh[t - off] : 0;
    __syncthreads();
    sh[t] += u;
    __syncthreads();
  }
  if (t < NBLK) blockoff[t] = sh[t] - v;
  if (t == 255) row_ptr[NN] = sh[255];
}

__global__ void rowptr_kernel(const int* __restrict__ cnt, const int* __restrict__ blockoff,
                              int* __restrict__ row_ptr) {
  __shared__ int sh[256];
  int t = threadIdx.x;
  int idx = blockIdx.x * 256 + t;
  int v = idx < NN ? cnt[idx] : 0;
  sh[t] = v;
  __syncthreads();
  for (int off = 1; off < 256; off <<= 1) {
    int u = (t >= off) ? sh[t - off] : 0;
    __syncthreads();
    sh[t] += u;
    __syncthreads();
  }
  if (idx < NN) row_ptr[idx] = blockoff[blockIdx.x] + sh[t] - v;
}

// pure read + ONE 8B store per edge (no atomic: rank precomputed in hist).
__global__ void scatter_kernel(const int* __restrict__ src, const int* __restrict__ dst,
                               const float* __restrict__ dist,
                               const int* __restrict__ row_ptr, const int* __restrict__ rank,
                               int2* __restrict__ csr_ew) {
  int e = blockIdx.x * blockDim.x + threadIdx.x;
  if (e >= NE) return;
  int pos = row_ptr[dst[e]] + rank[e];
  float dd = dist[e] + 1e-6f;
  float w = 1.0f / (dd * dd);
  csr_ew[pos] = make_int2(src[e], (int)__float_as_uint(w));
}

__global__ void wsum_kernel(const int* __restrict__ row_ptr, const int2* __restrict__ csr_ew,
                            float* __restrict__ wsum) {
  int n = blockIdx.x * blockDim.x + threadIdx.x;
  if (n >= NN) return;
  int s = row_ptr[n], e = row_ptr[n + 1];
  float acc = 0.f;
  for (int i = s; i < e; ++i) acc += __uint_as_float((unsigned)csr_ew[i].y);
  wsum[n] = acc;
}

// -------- fused per-layer: wave-per-node gather -> LDS -> MFMA linear -> hout --------
// Block = 16 waves = 16 nodes (TLP preserved: 40000 gather waves, unlike R12's
// 16-nodes-per-wave form). Phase 1: each wave runs the R14 4-edge/VMEM gather for
// ITS node, writes bf16 hi/lo row to LDS. One barrier. Phase 2: waves 0-7 each
// compute one 16x16 output tile (t = wave) from the shared LDS A-tile via
// split-bf16 MFMA (a*w ~= ah*wh + ah*wl + al*wh, fp32 acc) and store hout.
// D-layout: col(kout)=lane&15, row(node)=(lane>>4)*4+reg [guide §3, m89-verified].
// hin/hout double-buffered (blocks read random hin rows while others write hout).
__global__ void __launch_bounds__(1024) fused_layer_kernel(
    const __half* __restrict__ hin, const int* __restrict__ row_ptr,
    const int2* __restrict__ csr_ew,
    const unsigned short* __restrict__ whi, const unsigned short* __restrict__ wlo,
    const float* __restrict__ wsum, const float* __restrict__ b,
    __half* __restrict__ hout) {
  __shared__ __align__(16) unsigned short sAh[16][LSTRIDE];
  __shared__ __align__(16) unsigned short sAl[16][LSTRIDE];
  int wave = threadIdx.x >> 6;
  int lane = threadIdx.x & 63;
  int wid = blockIdx.x * 16 + wave;  // this wave's node

  // ---- phase 1: aggregate this wave's node (4 edges per VMEM instr) ----
  {
    int s = __builtin_amdgcn_readfirstlane(row_ptr[wid]);
    int e = __builtin_amdgcn_readfirstlane(row_ptr[wid + 1]);
    int g = lane >> 4;   // edge slot within a quad
    int k = lane & 15;   // col octet: cols [8k, 8k+8)
    const __half* hp = hin + k * 8;
    float a[8] = {0.f, 0.f, 0.f, 0.f, 0.f, 0.f, 0.f, 0.f};
    int i = s;
    for (; i + 16 <= e; i += 16) {  // clamp-free main strips
      uint4 hv[4];
      float wv[4];
#pragma unroll
      for (int u = 0; u < 4; ++u) {
        int2 p = csr_ew[i + u * 4 + g];
        wv[u] = __uint_as_float((unsigned)p.y);
        hv[u] = *reinterpret_cast<const uint4*>(hp + (size_t)p.x * HID);
      }
#pragma unroll
      for (int u = 0; u < 4; ++u) {
        const __half2* q = reinterpret_cast<const __half2*>(&hv[u]);
#pragma unroll
        for (int c = 0; c < 4; ++c) {
          float2 f = __half22float2(q[c]);
          a[2 * c] += wv[u] * f.x;
          a[2 * c + 1] += wv[u] * f.y;
        }
      }
    }
    for (; i < e; i += 4) {  // tail quads (clamped, w=0 pads vanish exactly)
      int j = i + g;
      int jc = j < e ? j : e - 1;
      int2 p = csr_ew[jc];
      float w = (j < e) ? __uint_as_float((unsigned)p.y) : 0.f;
      uint4 hv = *reinterpret_cast<const uint4*>(hp + (size_t)p.x * HID);
      const __half2* q = reinterpret_cast<const __half2*>(&hv);
#pragma unroll
      for (int c = 0; c < 4; ++c) {
        float2 f = __half22float2(q[c]);
        a[2 * c] += w * f.x;
        a[2 * c + 1] += w * f.y;
      }
    }
#pragma unroll
    for (int c = 0; c < 8; ++c) {
      a[c] += __shfl_xor(a[c], 16, 64);
      a[c] += __shfl_xor(a[c], 32, 64);
    }
    if (g == 0) {
      unsigned short hh[8], ll[8];
#pragma unroll
      for (int c = 0; c < 8; ++c) {
        hh[c] = f32_to_bf16_rne(a[c]);
        ll[c] = f32_to_bf16_rne(a[c] - bf16_to_f32(hh[c]));
      }
      *reinterpret_cast<uint4*>(&sAh[wave][k * 8]) = *reinterpret_cast<const uint4*>(hh);
      *reinterpret_cast<uint4*>(&sAl[wave][k * 8]) = *reinterpret_cast<const uint4*>(ll);
    }
  }
  __syncthreads();

  // ---- phase 2: waves 0-7 each compute one 16x16 output tile ----
  if (wave >= 8) return;
  int t = wave;
  int mrow = lane & 15;
  int kc = (lane >> 4) * 8;

  f32x4 acc = (f32x4){0.f, 0.f, 0.f, 0.f};
#pragma unroll
  for (int si = 0; si < 4; ++si) {
    int joff = si * 32 + kc;
    bf16x8 ah = *reinterpret_cast<const bf16x8*>(&sAh[mrow][joff]);
    bf16x8 al = *reinterpret_cast<const bf16x8*>(&sAl[mrow][joff]);
    bf16x8 bh = *reinterpret_cast<const bf16x8*>(whi + (t * 16 + mrow) * HID + joff);
    bf16x8 bl = *reinterpret_cast<const bf16x8*>(wlo + (t * 16 + mrow) * HID + joff);
    acc = __builtin_amdgcn_mfma_f32_16x16x32_bf16(ah, bh, acc, 0, 0, 0);
    acc = __builtin_amdgcn_mfma_f32_16x16x32_bf16(ah, bl, acc, 0, 0, 0);
    acc = __builtin_amdgcn_mfma_f32_16x16x32_bf16(al, bh, acc, 0, 0, 0);
  }

  int nodeBase = blockIdx.x * 16 + (lane >> 4) * 4;
  int kout = t * 16 + mrow;
  float bk = b[kout];
#pragma unroll
  for (int r = 0; r < 4; ++r) {
    float v = acc[r] + bk * wsum[nodeBase + r];
    hout[(nodeBase + r) * HID + kout] = __float2half(fmaxf(v, 0.f));
  }
}

// ---------------- cluster softmax head (wave per node) ----------------
__global__ void cluster_kernel(const __half* __restrict__ h, const float* __restrict__ cW,
                               const float* __restrict__ cb, float* __restrict__ out) {
  int wid = (blockIdx.x * blockDim.x + threadIdx.x) >> 6;
  int lane = threadIdx.x & 63;
  if (wid >= NN) return;
  float h0 = __half2float(h[wid * HID + lane]);
  float h1 = __half2float(h[wid * HID + 64 + lane]);
  float logit[3];
#pragma unroll
  for (int c = 0; c < 3; ++c) {
    float p = h0 * cW[c * HID + lane] + h1 * cW[c * HID + 64 + lane];
#pragma unroll
    for (int off = 32; off > 0; off >>= 1) p += __shfl_xor(p, off, 64);
    logit[c] = p + cb[c];
  }
  if (lane == 0) {
    float m = fmaxf(logit[0], fmaxf(logit[1], logit[2]));
    float e0 = expf(logit[0] - m), e1 = expf(logit[1] - m), e2 = expf(logit[2] - m);
    float inv = 1.0f / (e0 + e1 + e2);
    out[wid * 3 + 0] = e0 * inv;
    out[wid * 3 + 1] = e1 * inv;
    out[wid * 3 + 2] = e2 * inv;
  }
}

// ---------------- energy head: two-stage column reduction ----------------
__global__ void colsum_part_kernel(const __half* __restrict__ h, float* __restrict__ partial) {
  int t = threadIdx.x;
  int col = t & 127;
  int lane_id = blockIdx.x * 2 + (t >> 7);  // [0, 2048)
  float acc = 0.f;
  for (int r = lane_id; r < NN; r += 2048) acc += __half2float(h[r * HID + col]);
  partial[lane_id * HID + col] = acc;
}

__global__ void energy_final_kernel(const float* __restrict__ partial,
                                    const float* __restrict__ eW, const float* __restrict__ eb,
                                    float* __restrict__ out) {
  __shared__ float sh[8][HID];
  __shared__ float red[2];
  int t = threadIdx.x;
  int col = t & 127;
  int slot = t >> 7;  // 0..7
  float acc = 0.f;
  for (int i = 0; i < 256; ++i) acc += partial[(slot + 8 * i) * HID + col];
  sh[slot][col] = acc;
  __syncthreads();
  if (t < 128) {
    float s = 0.f;
#pragma unroll
    for (int j = 0; j < 8; ++j) s += sh[j][t];
    float v = s * (1.0f / NN) * eW[t];
#pragma unroll
    for (int off = 32; off > 0; off >>= 1) v += __shfl_xor(v, off, 64);
    if ((t & 63) == 0) red[t >> 6] = v;
  }
  __syncthreads();
  if (t == 0) {
    float e = red[0] + red[1] + eb[0];
    out[NN * 3] = e;
    out[NN * 3 + 1] = (e < -1.0f) ? 1.0f : 0.0f;
  }
}

extern "C" void kernel_launch(void* const* d_in, const int* in_sizes, int n_in,
                              void* d_out, int out_size, void* d_ws, size_t ws_size,
                              hipStream_t stream) {
  const float* x    = (const float*)d_in[0];
  const int*   ei   = (const int*)d_in[1];
  const float* dist = (const float*)d_in[2];
  const float* encW = (const float*)d_in[3];
  const float* encb = (const float*)d_in[4];
  const float* convW = (const float*)d_in[5];
  const float* convb = (const float*)d_in[6];
  const float* cW   = (const float*)d_in[7];
  const float* cb   = (const float*)d_in[8];
  const float* eW   = (const float*)d_in[9];
  const float* eb   = (const float*)d_in[10];
  float* out = (float*)d_out;

  // workspace layout (bytes)
  char* ws = (char*)d_ws;
  __half*         h1      = (__half*)        (ws + 0);           // 10,240,000
  __half*         h2      = (__half*)        (ws + 10240000);    // 10,240,000 (dbuf)
  char*           scratch = (char*)          (ws + 20480000);    // 10,240,000 (scan+colsum)
  int2*           csr_ew  = (int2*)          (ws + 30720000);    //  5,120,000
  int*            row_ptr = (int*)           (ws + 35840000);    //    160,064
  int*            cnt     = (int*)           (ws + 36000064);    //    160,000
  float*          wsum    = (float*)         (ws + 36160064);    //    160,000
  unsigned short* whi5    = (unsigned short*)(ws + 36320064);    //    163,840
  unsigned short* wlo5    = (unsigned short*)(ws + 36483904);    //    163,840
  int*            rank    = (int*)           (ws + 36647744);    //  2,560,000
  if (ws_size < (size_t)39207744) return;  // insufficient scratch — fail visibly

  int*   blocksum = (int*)scratch;
  int*   blockoff = (int*)scratch + 512;
  float* partial  = (float*)scratch;  // 2048*128 floats (used after CSR build)

  const int* srcI = ei;
  const int* dstI = ei + NE;

  hipMemsetAsync(cnt, 0, 160000, stream);

  encoder_wconv_kernel<<<20320, 256, 0, stream>>>(x, encW, encb, h1, convW, whi5, wlo5);

  hist_kernel<<<(NE + 255) / 256, 256, 0, stream>>>(dstI, cnt, rank);
  partial_kernel<<<NBLK, 256, 0, stream>>>(cnt, blocksum);
  scan_small_kernel<<<1, 256, 0, stream>>>(blocksum, blockoff, row_ptr);
  rowptr_kernel<<<NBLK, 256, 0, stream>>>(cnt, blockoff, row_ptr);
  scatter_kernel<<<(NE + 255) / 256, 256, 0, stream>>>(srcI, dstI, dist, row_ptr, rank, csr_ew);
  wsum_kernel<<<(NN + 255) / 256, 256, 0, stream>>>(row_ptr, csr_ew, wsum);

  __half* hin = h1;
  __half* hout = h2;
  for (int l = 0; l < NL; ++l) {
    fused_layer_kernel<<<NN / 16, 1024, 0, stream>>>(hin, row_ptr, csr_ew,
                                                     whi5 + (size_t)l * HID * HID,
                                                     wlo5 + (size_t)l * HID * HID,
                                                     wsum, convb + (size_t)l * HID, hout);
    __half* tmp = hin; hin = hout; hout = tmp;
  }
  // after 5 layers, final h is in hin

  cluster_kernel<<<(NN * 64 + 255) / 256, 256, 0, stream>>>(hin, cW, cb, out);
  colsum_part_kernel<<<1024, 256, 0, stream>>>(hin, partial);
  energy_final_kernel<<<1, 1024, 0, stream>>>(partial, eW, eb, out);
}